// Round 1
// baseline (188.663 us; speedup 1.0000x reference)
//
#include <hip/hip_runtime.h>

// Bidirectional GRU (H=32, input=1, B=2048, T=512) + MLP head, fully fused.
//
// Reference takes out[:, -1, :] = concat(h_fwd after T steps, h_bwd after ONE
// step from h0=0 on x[T-1]) -> only the forward scan is sequential; W_hh_b is
// entirely unused.
//
// R12 = R11 with the h broadcast moved from LDS into registers.
//
// Model (R8..R11): wall 532 cyc/step = ~325 issue + ~207 stall; the stall is
// dominated by the h LDS round-trip (ds_write_b16 -> wave_barrier -> 4x
// broadcast ds_read_b128, ~120-130 cyc) that sits on the recurrence and is
// unhidable at 1 wave/SIMD. R12 replaces it with an in-register butterfly
// all-gather:
//   * lane g owns h[g] (f16). Pack {h[g], h[g^1]} via DPP quad_perm xor1.
//   * Double the register set with DPP xor2 (quad_perm 0x4E), lane^7
//     (row_half_mirror 0x141), lane^15 (row_mirror 0x140): 8 regs = pairs 0..7
//     of the 16-lane group. One ds_swizzle xor16 (0x401F) + the same 3 DPP
//     stages: pairs 8..15. XOR offsets compose, so reg k holds pair
//     (g>>1)^poff[k], within-pair order (g&1)^oflip[k] -- static per lane.
//   * Weights are loaded PRE-PERMUTED per lane to match (poff/oflip tables),
//     so the FDOT16 chains are unchanged. Numerics identical to R11.
// Latency to first usable pair ~15 cyc (vs ~140), swizzle latency hides under
// the 24 dot2s that only consume tree-1 regs. Net: -~120 stall, +~25 issue.
//
// Structure (unchanged from R11 otherwise):
//   * 32 lanes per row, full 32-wide f16 dot2 per lane, no shfl; 2 rows per
//     wave as half-waves; 256 blocks x 256 thr = 1024 waves = 1 wave/SIMD.
//   * Weights f16 packed (16 h2 per gate = 48 VGPRs), pre-scaled into exp2
//     domain (r/z by -log2e, n by 2log2e), pinned via inline-asm "+v".
//   * sigmoid = v_rcp(1+v_exp2(.)), tanh = 1-2*v_rcp(1+v_exp2(.)).
//   * x staged in LDS f32, consumed as vf4 per 4 steps (prefetched); x-term
//     FMAs for all 4 unrolled steps hoisted to the tg-loop top.

typedef float vf2 __attribute__((ext_vector_type(2)));
typedef float vf4 __attribute__((ext_vector_type(4)));
typedef _Float16 f16;
typedef f16 h2 __attribute__((ext_vector_type(2)));

#define TT 512
#define HH 32

// inline-asm defs are not rematerializable: forces a real VGPR def here.
#define PIN(v) asm volatile("" : "+v"(v))

#define LOG2E 1.44269504f

__device__ __forceinline__ float fast_sigm(float a) {   // sigmoid(a)
  return __builtin_amdgcn_rcpf(1.0f + __builtin_amdgcn_exp2f(-LOG2E * a));
}
__device__ __forceinline__ float fast_tanh(float a) {   // tanh(a)
  return __builtin_fmaf(-2.0f,
      __builtin_amdgcn_rcpf(1.0f + __builtin_amdgcn_exp2f(2.0f * LOG2E * a)),
      1.0f);
}

// DPP lane-permute (ctrl must be a compile-time constant -> template).
template<int CTRL>
__device__ __forceinline__ unsigned dppu(unsigned x) {
  return (unsigned)__builtin_amdgcn_update_dpp((int)x, (int)x, CTRL, 0xF, 0xF, false);
}
__device__ __forceinline__ h2 bch2(unsigned x) {
  union { unsigned u; h2 h; } c; c.u = x; return c.h;
}

// Weight pair for butterfly slot: pair index (pr ^ poff), swapped iff (oo ^ of).
__device__ __forceinline__ h2 packw(const vf2* Wp, int base, int pr, int oo,
                                    int poff, int of, float s) {
  vf2 e = Wp[base + (pr ^ poff)];
  float lo = (oo ^ of) ? e.y : e.x;
  float hi = (oo ^ of) ? e.x : e.y;
  h2 r = {(f16)(lo * s), (f16)(hi * s)};
  return r;
}

// Butterfly slot tables (see derivation in header):
//   slot:   0  1  2  3  4  5  6  7  8  9  A  B  C  D  E  F
//   poff:   0  1  3  2  7  6  4  5  8  9 11 10 15 14 12 13
//   oflip:  0  0  1  1  1  1  0  0  0  0  1  1  1  1  0  0
#define LDWB(P, BASE, S) \
  h2 P##0=packw(Wp,(BASE),pr,oo, 0,0,(S)), P##1=packw(Wp,(BASE),pr,oo, 1,0,(S)), \
     P##2=packw(Wp,(BASE),pr,oo, 3,1,(S)), P##3=packw(Wp,(BASE),pr,oo, 2,1,(S)), \
     P##4=packw(Wp,(BASE),pr,oo, 7,1,(S)), P##5=packw(Wp,(BASE),pr,oo, 6,1,(S)), \
     P##6=packw(Wp,(BASE),pr,oo, 4,0,(S)), P##7=packw(Wp,(BASE),pr,oo, 5,0,(S)), \
     P##8=packw(Wp,(BASE),pr,oo, 8,0,(S)), P##9=packw(Wp,(BASE),pr,oo, 9,0,(S)), \
     P##A=packw(Wp,(BASE),pr,oo,11,1,(S)), P##B=packw(Wp,(BASE),pr,oo,10,1,(S)), \
     P##C=packw(Wp,(BASE),pr,oo,15,1,(S)), P##D=packw(Wp,(BASE),pr,oo,14,1,(S)), \
     P##E=packw(Wp,(BASE),pr,oo,12,0,(S)), P##F=packw(Wp,(BASE),pr,oo,13,0,(S)); \
  PIN(P##0);PIN(P##1);PIN(P##2);PIN(P##3);PIN(P##4);PIN(P##5);PIN(P##6);PIN(P##7); \
  PIN(P##8);PIN(P##9);PIN(P##A);PIN(P##B);PIN(P##C);PIN(P##D);PIN(P##E);PIN(P##F)

// 16 v_dot2_f32_f16 of (q0..qF).(P0..PF) into two chains A0,A1; A0 seeded.
#define FDOT16(A0, A1, P, SEED) \
  float A0 = __builtin_amdgcn_fdot2(q0, P##0, (SEED), false); \
  float A1 = __builtin_amdgcn_fdot2(q1, P##1, 0.0f, false); \
  A0 = __builtin_amdgcn_fdot2(q2, P##2, A0, false);  A1 = __builtin_amdgcn_fdot2(q3, P##3, A1, false); \
  A0 = __builtin_amdgcn_fdot2(q4, P##4, A0, false);  A1 = __builtin_amdgcn_fdot2(q5, P##5, A1, false); \
  A0 = __builtin_amdgcn_fdot2(q6, P##6, A0, false);  A1 = __builtin_amdgcn_fdot2(q7, P##7, A1, false); \
  A0 = __builtin_amdgcn_fdot2(q8, P##8, A0, false);  A1 = __builtin_amdgcn_fdot2(q9, P##9, A1, false); \
  A0 = __builtin_amdgcn_fdot2(qA, P##A, A0, false);  A1 = __builtin_amdgcn_fdot2(qB, P##B, A1, false); \
  A0 = __builtin_amdgcn_fdot2(qC, P##C, A0, false);  A1 = __builtin_amdgcn_fdot2(qD, P##D, A1, false); \
  A0 = __builtin_amdgcn_fdot2(qE, P##E, A0, false);  A1 = __builtin_amdgcn_fdot2(qF, P##F, A1, false)

__global__ __launch_bounds__(256)
__attribute__((amdgpu_waves_per_eu(1, 1)))
void gru_bidir_head(const float* __restrict__ X,
                    const float* __restrict__ Wih_f, const float* __restrict__ Whh_f,
                    const float* __restrict__ bih_f, const float* __restrict__ bhh_f,
                    const float* __restrict__ Wih_b,
                    const float* __restrict__ bih_b, const float* __restrict__ bhh_b,
                    const float* __restrict__ W1, const float* __restrict__ b1,
                    const float* __restrict__ W2, const float* __restrict__ b2,
                    float* __restrict__ out)
{
  __shared__ float xbuf[8][TT];        // staged input rows (16 KB)
  __shared__ float obuf[8][64];        // [row][h_f(32) | h_b(32)] (2 KB)

  const int g  = threadIdx.x & 31;     // lane within row group = output index i
  const int rs = threadIdx.x >> 5;     // row slot in block (0..7)
  const int b  = (blockIdx.x << 3) + rs;

  // --- stage this row of X into LDS (4 x vf4 per lane, coalesced) ---
  const vf4* Xr4 = (const vf4*)(X + (size_t)b * TT);
  vf4* xb4 = (vf4*)&xbuf[rs][0];
  #pragma unroll
  for (int q = 0; q < 4; ++q) xb4[g + 32 * q] = Xr4[g + 32 * q];

  // --- per-lane weights: W_hh rows g (r), 32+g (z), 64+g (n); pre-scaled
  //     into exp2 domain, packed f16, PRE-PERMUTED to the butterfly slot
  //     order (48 VGPRs, pinned) ---
  const vf2* Wp = (const vf2*)Whh_f;   // row stride = 16 vf2
  const float s1 = -LOG2E;             // r,z: sigmoid domain (negated)
  const float s2 = 2.0f * LOG2E;       // n: tanh domain
  const int pr = g >> 1;               // own h-pair index
  const int oo = g & 1;                // own within-pair order
  LDWB(Wr, (g)        * 16, s1);
  LDWB(Wz, (HH + g)   * 16, s1);
  LDWB(Wn, (2*HH + g) * 16, s2);

  float xwr = Wih_f[g] * s1, xwz = Wih_f[HH + g] * s1, xwn = Wih_f[2*HH + g] * s2;
  float cbr = (bih_f[g]      + bhh_f[g])      * s1;
  float cbz = (bih_f[HH + g] + bhh_f[HH + g]) * s1;
  float cbn = bih_f[2*HH + g] * s2;            // n: b_ih term (with x)
  float cbh = bhh_f[2*HH + g] * s2;            // n: b_hh term (inside r*(...))
  PIN(xwr); PIN(xwz); PIN(xwn); PIN(cbr); PIN(cbz); PIN(cbn); PIN(cbh);

  float h = 0.0f;

  const vf4* xv = (const vf4*)&xbuf[rs][0];
  vf4 x4 = xv[0];

  #pragma unroll 1
  for (int tg = 0; tg < TT / 4; ++tg) {
    const vf4 x4n = xv[tg + 1 < TT / 4 ? tg + 1 : tg];   // off critical path

    // hoist ALL x-dependent terms for the 4 sub-steps (off the serial chain)
    float sr0 = __builtin_fmaf(x4.x, xwr, cbr), sz0 = __builtin_fmaf(x4.x, xwz, cbz),
          sn0 = __builtin_fmaf(x4.x, xwn, cbn);
    float sr1 = __builtin_fmaf(x4.y, xwr, cbr), sz1 = __builtin_fmaf(x4.y, xwz, cbz),
          sn1 = __builtin_fmaf(x4.y, xwn, cbn);
    float sr2 = __builtin_fmaf(x4.z, xwr, cbr), sz2 = __builtin_fmaf(x4.z, xwz, cbz),
          sn2 = __builtin_fmaf(x4.z, xwn, cbn);
    float sr3 = __builtin_fmaf(x4.w, xwr, cbr), sz3 = __builtin_fmaf(x4.w, xwz, cbz),
          sn3 = __builtin_fmaf(x4.w, xwn, cbn);

    #pragma unroll
    for (int u = 0; u < 4; ++u) {
      const float sr = (u == 0) ? sr0 : (u == 1) ? sr1 : (u == 2) ? sr2 : sr3;
      const float sz = (u == 0) ? sz0 : (u == 1) ? sz1 : (u == 2) ? sz2 : sz3;
      const float sn = (u == 0) ? sn0 : (u == 1) ? sn1 : (u == 2) ? sn2 : sn3;

      // --- in-register butterfly all-gather of h (f16) within the 32-half ---
      unsigned uh; { union { f16 f; unsigned short u16; } cc; cc.f = (f16)h; uh = cc.u16; }
      const unsigned T1 = dppu<0xB1>(uh);                  // quad_perm xor1
      const unsigned A0 = (uh & 0xffffu) | (T1 << 16);     // pair pr, order oo
      const unsigned E0 = (unsigned)__builtin_amdgcn_ds_swizzle((int)A0, 0x401F); // lane^16
      const unsigned B0 = dppu<0x4E>(A0);                  // xor2  -> pair^1
      const unsigned C0 = dppu<0x141>(A0);                 // xor7  -> pair^3, ord^1
      const unsigned C1 = dppu<0x141>(B0);                 //       -> pair^2, ord^1
      const unsigned D0 = dppu<0x140>(A0);                 // xor15 -> pair^7, ord^1
      const unsigned D1 = dppu<0x140>(B0);                 //       -> pair^6, ord^1
      const unsigned D2 = dppu<0x140>(C0);                 //       -> pair^4
      const unsigned D3 = dppu<0x140>(C1);                 //       -> pair^5
      const unsigned F0 = dppu<0x4E>(E0);                  //       -> pair^9
      const unsigned G0 = dppu<0x141>(E0);                 //       -> pair^11, ord^1
      const unsigned G1 = dppu<0x141>(F0);                 //       -> pair^10, ord^1
      const unsigned H0u = dppu<0x140>(E0);                //       -> pair^15, ord^1
      const unsigned H1u = dppu<0x140>(F0);                //       -> pair^14, ord^1
      const unsigned H2u = dppu<0x140>(G0);                //       -> pair^12
      const unsigned H3u = dppu<0x140>(G1);                //       -> pair^13

      const h2 q0 = bch2(A0),  q1 = bch2(B0),  q2 = bch2(C0),  q3 = bch2(C1),
               q4 = bch2(D0),  q5 = bch2(D1),  q6 = bch2(D2),  q7 = bch2(D3),
               q8 = bch2(E0),  q9 = bch2(F0),  qA = bch2(G0),  qB = bch2(G1),
               qC = bch2(H0u), qD = bch2(H1u), qE = bch2(H2u), qF = bch2(H3u);

      FDOT16(Ra, Rb, Wr, sr);
      FDOT16(Za, Zb, Wz, sz);
      FDOT16(Na, Nb, Wn, cbh);

      const float ar = Ra + Rb;                  // includes x-term + bias
      const float az = Za + Zb;
      const float r = __builtin_amdgcn_rcpf(1.0f + __builtin_amdgcn_exp2f(ar));
      const float z = __builtin_amdgcn_rcpf(1.0f + __builtin_amdgcn_exp2f(az));
      const float y = __builtin_fmaf(r, Na + Nb, sn);
      const float n = __builtin_fmaf(-2.0f,
          __builtin_amdgcn_rcpf(1.0f + __builtin_amdgcn_exp2f(y)), 1.0f);
      h = __builtin_fmaf(z, h - n, n);           // (1-z)*n + z*h
    }
    x4 = x4n;
  }

  // --- backward direction: exactly ONE GRU step from h0=0 on x[T-1] ---
  const float xl  = xbuf[rs][TT - 1];
  const float rb  = fast_sigm(__builtin_fmaf(xl, Wih_b[g],      bih_b[g]      + bhh_b[g]));
  const float zb  = fast_sigm(__builtin_fmaf(xl, Wih_b[HH + g], bih_b[HH + g] + bhh_b[HH + g]));
  const float xnb = __builtin_fmaf(xl, Wih_b[2*HH + g], bih_b[2*HH + g]);
  const float nb  = fast_tanh(__builtin_fmaf(rb, bhh_b[2*HH + g], xnb));
  const float hb  = nb - zb * nb;                // (1-zb)*nb + zb*0

  obuf[rs][g]      = h;                          // h_f (full fp32 state)
  obuf[rs][32 + g] = hb;                         // h_b
  __builtin_amdgcn_wave_barrier();

  // --- MLP head: sigmoid(W2 @ relu(W1 @ [h_f,h_b] + b1) + b2) ---
  const int j = g & 15;                          // lanes 16..31 duplicate
  const vf4* W1r = (const vf4*)(W1 + j * 64);
  const vf4* hc  = (const vf4*)&obuf[rs][0];
  vf4 a4 = W1r[0] * hc[0];
  #pragma unroll
  for (int q = 1; q < 16; ++q)
    a4 = __builtin_elementwise_fma(W1r[q], hc[q], a4);
  float acc = b1[j] + (a4.x + a4.y) + (a4.z + a4.w);
  float h1 = fmaxf(acc, 0.0f) * W2[j];
  h1 += __shfl_down(h1, 8, 16);
  h1 += __shfl_down(h1, 4, 16);
  h1 += __shfl_down(h1, 2, 16);
  h1 += __shfl_down(h1, 1, 16);
  if (g == 0) out[b] = fast_sigm(h1 + b2[0]);
}

extern "C" void kernel_launch(void* const* d_in, const int* in_sizes, int n_in,
                              void* d_out, int out_size, void* d_ws, size_t ws_size,
                              hipStream_t stream) {
  const float* X     = (const float*)d_in[0];
  const float* Wih_f = (const float*)d_in[1];
  const float* Whh_f = (const float*)d_in[2];
  const float* bih_f = (const float*)d_in[3];
  const float* bhh_f = (const float*)d_in[4];
  const float* Wih_b = (const float*)d_in[5];
  // d_in[6] = W_hh_b: unused — backward direction runs exactly one step from h0=0.
  const float* bih_b = (const float*)d_in[7];
  const float* bhh_b = (const float*)d_in[8];
  const float* W1    = (const float*)d_in[9];
  const float* b1    = (const float*)d_in[10];
  const float* W2    = (const float*)d_in[11];
  const float* b2    = (const float*)d_in[12];
  float* out = (float*)d_out;

  // 2048 rows / 8 rows per 256-thread block = 256 blocks = 1 block/CU,
  // 1024 waves = 1 wave/SIMD (2 rows per wave as half-waves).
  gru_bidir_head<<<256, 256, 0, stream>>>(X, Wih_f, Whh_f, bih_f, bhh_f,
                                          Wih_b, bih_b, bhh_b, W1, b1, W2, b2, out);
}